// Round 19
// baseline (209.244 us; speedup 1.0000x reference)
//
#include <hip/hip_runtime.h>
#include <hip/hip_bf16.h>

typedef __attribute__((ext_vector_type(8))) short short8;
typedef __attribute__((ext_vector_type(4))) short short4v;
typedef __attribute__((ext_vector_type(4))) unsigned uint4v;
typedef __attribute__((ext_vector_type(4))) float f32x4;
typedef __attribute__((ext_vector_type(16))) float f32x16;
typedef unsigned short u16;

#define ZERO16 (f32x16){0,0,0,0,0,0,0,0,0,0,0,0,0,0,0,0}

__device__ __forceinline__ float b2f(u16 h) {
    unsigned u = ((unsigned)h) << 16;
    float f; __builtin_memcpy(&f, &u, 4); return f;
}
__device__ __forceinline__ u16 f2b(float f) {   // RTNE via HIP intrinsic
    __hip_bfloat16 h = __float2bfloat16(f);
    u16 r; __builtin_memcpy(&r, &h, 2); return r;
}
__device__ __forceinline__ void gload16(const void* g, void* l) {
    __builtin_amdgcn_global_load_lds(
        (const __attribute__((address_space(1))) unsigned*)g,
        (__attribute__((address_space(3))) unsigned*)l, 16, 0, 0);
}
__device__ __forceinline__ unsigned cvtpk_bf16(float lo, float hi) {
    unsigned d;
    asm("v_cvt_pk_bf16_f32 %0, %1, %2" : "=v"(d) : "v"(lo), "v"(hi));
    return d;
}

// ---------------- problem constants ----------------
#define M_VALID 2640          // B*S*T tokens
#define M_PAD   2688          // 21 * 128
#define DH      1024
#define CIMG    3072
#define NHEAD   16
#define NT      84            // 32-token tiles (2688 tokens)
#define QG      21            // q-tile groups of 4 (4 waves/block)
#define NSPLIT  3
#define TILES_PER_SPLIT 28    // 3*28 = 84 tiles
#define LOG2E   1.4426950408889634f

// ---------------- per-frame bias for gemm1: bias1t[t] = b1 + mouse[t] @ W1[3072:] ----------------
__global__ __launch_bounds__(256) void bias1t_kernel(
    const float* __restrict__ w1, const float* __restrict__ b1,
    const float* __restrict__ cond, float* __restrict__ bias1t)
{
    int t = blockIdx.x;                       // 0..2
    int col = blockIdx.y * 256 + threadIdx.x;
    float v = b1[col];
#pragma unroll
    for (int j = 0; j < 24; j++) {
        int f = t * 4 + (j >> 1);             // row in mouse_padded (first 8 zero)
        if (f >= 8) v += cond[(f - 8) * 2 + (j & 1)] * w1[(size_t)(3072 + j) * DH + col];
    }
    bias1t[t * DH + col] = v;
}

// ---------------- all 4 weight transposes, one dispatch ----------------
__global__ __launch_bounds__(256) void transpose_all_kernel(
    const float* __restrict__ w1, const float* __restrict__ w2,
    const float* __restrict__ wqkv, const float* __restrict__ wproj,
    u16* __restrict__ w1t, u16* __restrict__ w2t,
    u16* __restrict__ wqkvt, u16* __restrict__ wprojt)
{
    int b = blockIdx.x;
    const float* W; u16* Wt; int K, N, ldt, nx;
    if (b < 3072)      {            W = w1;    Wt = w1t;    K = 3072; N = DH;   ldt = 3072; nx = 32; }
    else if (b < 4096) { b -= 3072; W = w2;    Wt = w2t;    K = DH;   N = DH;   ldt = DH;   nx = 32; }
    else if (b < 7168) { b -= 4096; W = wqkv;  Wt = wqkvt;  K = DH;   N = 3072; ldt = DH;   nx = 96; }
    else               { b -= 7168; W = wproj; Wt = wprojt; K = DH;   N = CIMG; ldt = DH;   nx = 96; }
    __shared__ float t[32][33];
    int n0 = (b % nx) * 32, k0 = (b / nx) * 32;
    int x = threadIdx.x & 31, y0 = threadIdx.x >> 5;   // 32x8
    for (int yy = y0; yy < 32; yy += 8) {
        int k = k0 + yy, n = n0 + x;
        t[yy][x] = (k < K && n < N) ? W[(size_t)k * N + n] : 0.f;
    }
    __syncthreads();
    for (int yy = y0; yy < 32; yy += 8) {
        int n = n0 + yy, k = k0 + x;
        if (n < N && k < ldt) Wt[(size_t)n * ldt + k] = f2b(t[x][yy]);
    }
}

// ---------------- GEMM: C[M][N] = A[M][K] @ Bt[N][K]^T  (bf16 in, f32 acc) ----------------
// 2-phase pipeline, BK=64 dbuf LDS, XOR-16B swizzle, XCD swizzle, LDS-bounce epilogue.
// ACVT: A is fp32, converted to bf16 in registers during staging (row clamped to M_VALID-1).
// EPI 0: per-(row%3) bias + GELU -> bf16. EPI 1: bias -> bf16. EPI 2: bias+resid -> f32.
template<int EPI, int BM, int BN, bool ACVT>
__global__ __launch_bounds__(256) void gemm_kernel(
    const void* __restrict__ Araw, const u16* __restrict__ Bt,
    const float* __restrict__ bias, const float* __restrict__ resid,
    u16* __restrict__ Cb, float* __restrict__ Cf,
    int N, int K, int lda, int ldb, int Mvalid)
{
    constexpr int MI  = BM / 32;
    constexpr int NJ  = BN / 32;
    constexpr int CA  = BM / 32;
    constexpr int CB  = BN / 32;
    constexpr unsigned ABYTES = BM * 128;
    constexpr unsigned BBYTES = BN * 128;
    constexpr unsigned STG = 2 * (ABYTES + BBYTES);
    constexpr unsigned CTW = BN + 4;
    constexpr unsigned CTB = BM * CTW * 4;
    constexpr int TPR = 256 / BM;
    __shared__ __align__(16) char smem[STG > CTB ? STG : CTB];

    const int tid = threadIdx.x;
    const int lane = tid & 63, wid = tid >> 6;
    const int l15 = lane & 15, l4 = lane >> 4;

    const int nx = N / BN;
    const int nwg = nx * (M_PAD / BM);
    const int bid = blockIdx.x;
    const int wgid = (bid & 7) * (nwg >> 3) + (bid >> 3);
    const int m0 = (wgid / nx) * BM, n0 = (wgid % nx) * BN;

    const int wr = (wid >> 1) * (BM / 2), wc = (wid & 1) * (BN / 2);

    const int srow = lane >> 3;
    const int scol = ((lane & 7) ^ (lane >> 3)) << 3;

    f32x4 acc[MI][NJ];
#pragma unroll
    for (int i = 0; i < MI; i++)
#pragma unroll
        for (int j = 0; j < NJ; j++) acc[i][j] = (f32x4){0.f, 0.f, 0.f, 0.f};

    const int nt = K >> 6;

    auto stage = [&](int buf, int k0) {
        char* Ab = smem + buf * ABYTES;
        char* Bb = smem + 2 * ABYTES + buf * BBYTES;
#pragma unroll
        for (int i = 0; i < CA; i++) {
            int c = wid * CA + i;
            int arow = m0 + c * 8 + srow;
            if (ACVT) {
                if (arow > M_VALID - 1) arow = M_VALID - 1;   // x has only M_VALID rows
                const float* src = (const float*)Araw + (size_t)arow * lda + k0 + scol;
                float4 v0 = *(const float4*)src;
                float4 v1 = *(const float4*)(src + 4);
                uint4v u;
                u[0] = cvtpk_bf16(v0.x, v0.y); u[1] = cvtpk_bf16(v0.z, v0.w);
                u[2] = cvtpk_bf16(v1.x, v1.y); u[3] = cvtpk_bf16(v1.z, v1.w);
                *(uint4v*)(Ab + c * 1024 + lane * 16) = u;
            } else {
                gload16((const u16*)Araw + (size_t)arow * lda + k0 + scol,
                        Ab + c * 1024 + lane * 16);
            }
        }
#pragma unroll
        for (int i = 0; i < CB; i++) {
            int c = wid * CB + i;
            gload16(Bt + (size_t)(n0 + c * 8 + srow) * ldb + k0 + scol,
                    Bb + c * 1024 + lane * 16);
        }
    };

    stage(0, 0);
    __syncthreads();
    int cur = 0;
    for (int t = 0; t < nt; t++) {
        if (t + 1 < nt) stage(cur ^ 1, (t + 1) * 64);
        const char* Ab = smem + cur * ABYTES;
        const char* Bb = smem + 2 * ABYTES + cur * BBYTES;
#pragma unroll
        for (int ki = 0; ki < 2; ki++) {
            short8 af[MI], bfr[NJ];
#pragma unroll
            for (int i = 0; i < MI; i++) {
                int row = wr + i * 16 + l15;
                af[i] = *(const short8*)(Ab + row * 128 + (((ki * 4 + l4) ^ (l15 & 7)) << 4));
            }
#pragma unroll
            for (int j = 0; j < NJ; j++) {
                int row = wc + j * 16 + l15;
                bfr[j] = *(const short8*)(Bb + row * 128 + (((ki * 4 + l4) ^ (l15 & 7)) << 4));
            }
            __builtin_amdgcn_s_setprio(1);
#pragma unroll
            for (int i = 0; i < MI; i++)
#pragma unroll
                for (int j = 0; j < NJ; j++)
                    acc[i][j] = __builtin_amdgcn_mfma_f32_16x16x32_bf16(af[i], bfr[j], acc[i][j], 0, 0, 0);
            __builtin_amdgcn_s_setprio(0);
        }
        __syncthreads();
        cur ^= 1;
    }

    // ---- LDS-bounce epilogue ----
    float* Ct = (float*)smem;
#pragma unroll
    for (int i = 0; i < MI; i++)
#pragma unroll
        for (int j = 0; j < NJ; j++)
#pragma unroll
            for (int r = 0; r < 4; r++)
                Ct[(wr + i * 16 + l4 * 4 + r) * CTW + wc + j * 16 + l15] = acc[i][j][r];
    __syncthreads();

    const int row = tid / TPR;
    const int cb  = (tid % TPR) * (BN / TPR);
    const int grow = m0 + row;
    const int gcol = n0 + cb;
    if (EPI == 2) {
        if (grow < Mvalid) {
#pragma unroll
            for (int u = 0; u < BN / (4 * TPR); u++) {
                f32x4 v = *(const f32x4*)&Ct[row * CTW + cb + u * 4];
                float4 bv = *(const float4*)&bias[gcol + u * 4];
                float4 rv = *(const float4*)&resid[(size_t)grow * N + gcol + u * 4];
                float4 o;
                o.x = v[0] + bv.x + rv.x; o.y = v[1] + bv.y + rv.y;
                o.z = v[2] + bv.z + rv.z; o.w = v[3] + bv.w + rv.w;
                *(float4*)&Cf[(size_t)grow * N + gcol + u * 4] = o;
            }
        }
    } else {
        const float* bb = bias + (EPI == 0 ? (size_t)(grow % 3) * N : 0);
        u16 tmp[BN / TPR];
#pragma unroll
        for (int u = 0; u < BN / (4 * TPR); u++) {
            f32x4 v = *(const f32x4*)&Ct[row * CTW + cb + u * 4];
            float4 bv = *(const float4*)&bb[gcol + u * 4];
#pragma unroll
            for (int e = 0; e < 4; e++) {
                float val = v[e] + ((const float*)&bv)[e];
                if (EPI == 0) {
                    float tt = val + 0.044715f * val * val * val;
                    val = 0.5f * val * (1.0f + tanhf(0.7978845608028654f * tt));
                }
                tmp[u * 4 + e] = f2b(val);
            }
        }
#pragma unroll
        for (int u = 0; u < BN / (8 * TPR); u++)
            *(short8*)(Cb + (size_t)grow * N + gcol + u * 8) = *(const short8*)&tmp[u * 8];
    }
}

// ---------------- LayerNorm over 1024 (bf16 -> bf16) ----------------
__global__ __launch_bounds__(256) void ln_kernel(
    const u16* __restrict__ h2, const float* __restrict__ g,
    const float* __restrict__ b, u16* __restrict__ out)
{
    int row = blockIdx.x;
    int tid = threadIdx.x;
    const u16* p = h2 + (size_t)row * DH;
    float v[4];
#pragma unroll
    for (int i = 0; i < 4; i++) v[i] = b2f(p[tid * 4 + i]);
    float s1 = v[0] + v[1] + v[2] + v[3];
    float s2 = v[0]*v[0] + v[1]*v[1] + v[2]*v[2] + v[3]*v[3];
    for (int m = 1; m < 64; m <<= 1) { s1 += __shfl_xor(s1, m); s2 += __shfl_xor(s2, m); }
    __shared__ float a1[4], a2[4];
    int w = tid >> 6;
    if ((tid & 63) == 0) { a1[w] = s1; a2[w] = s2; }
    __syncthreads();
    s1 = a1[0] + a1[1] + a1[2] + a1[3];
    s2 = a2[0] + a2[1] + a2[2] + a2[3];
    float mean = s1 * (1.0f / 1024.0f);
    float var = s2 * (1.0f / 1024.0f) - mean * mean;
    float rs = rsqrtf(var + 1e-5f);
    u16* q = out + (size_t)row * DH;
#pragma unroll
    for (int i = 0; i < 4; i++) {
        int c = tid * 4 + i;
        q[c] = f2b((v[i] - mean) * rs * g[c] + b[c]);
    }
}

// ---------------- fragmentize: RMSNorm(q,k) + MFMA-fragment layout for Q,K,V ----------------
__global__ __launch_bounds__(256) void fragmentize_kernel(
    const u16* __restrict__ qkv, const float* __restrict__ qw, const float* __restrict__ kw,
    u16* __restrict__ Qf, u16* __restrict__ Kf, u16* __restrict__ Vf)
{
    __shared__ u16 Vlds[8 * 32 * 80];    // [hh][token][dim], row stride 80
    const int kt = blockIdx.x;           // 0..NT-1
    const int hg = blockIdx.y;           // 0..1 (8 heads each)
    const int tid = threadIdx.x;
    const int t32 = tid >> 3, c8 = tid & 7;
    const int n = kt * 32 + t32;
    const u16* row = qkv + (size_t)n * 3072;

#pragma unroll
    for (int hh = 0; hh < 8; hh++) {
        short8 v = *(const short8*)(row + 2048 + (hg * 8 + hh) * 64 + c8 * 8);
        *(short8*)(&Vlds[(hh * 32 + t32) * 80 + c8 * 8]) = v;
    }

    float sq[8], sk[8];
#pragma unroll
    for (int hh = 0; hh < 8; hh++) {
        int h = hg * 8 + hh;
        short8 qv = *(const short8*)(row + h * 64 + c8 * 8);
        short8 kv = *(const short8*)(row + 1024 + h * 64 + c8 * 8);
        float aq = 0.f, ak = 0.f;
#pragma unroll
        for (int e = 0; e < 8; e++) {
            float fq = b2f((u16)qv[e]); aq += fq * fq;
            float fk = b2f((u16)kv[e]); ak += fk * fk;
        }
        sq[hh] = aq; sk[hh] = ak;
    }
#pragma unroll
    for (int m = 1; m < 8; m <<= 1) {
#pragma unroll
        for (int hh = 0; hh < 8; hh++) {
            sq[hh] += __shfl_xor(sq[hh], m);
            sk[hh] += __shfl_xor(sk[hh], m);
        }
    }

    float qwv[8], kwv[8];
#pragma unroll
    for (int e = 0; e < 8; e++) { qwv[e] = qw[c8 * 8 + e]; kwv[e] = kw[c8 * 8 + e]; }

#pragma unroll
    for (int hh = 0; hh < 8; hh++) {
        int h = hg * 8 + hh;
        float rq = rsqrtf(sq[hh] * (1.0f / 64.0f) + 1e-6f) * (0.125f * LOG2E);
        float rk = rsqrtf(sk[hh] * (1.0f / 64.0f) + 1e-6f);
        short8 qv = *(const short8*)(row + h * 64 + c8 * 8);
        short8 kv = *(const short8*)(row + 1024 + h * 64 + c8 * 8);
        short8 qo, ko;
#pragma unroll
        for (int e = 0; e < 8; e++) {
            qo[e] = (short)f2b(b2f((u16)qv[e]) * rq * qwv[e]);
            ko[e] = (short)f2b(b2f((u16)kv[e]) * rk * kwv[e]);
        }
        size_t base = (((size_t)(h * NT + kt) * 4 + (c8 >> 1)) << 9) + t32 * 16 + (c8 & 1) * 8;
        *(short8*)(Qf + base) = qo;
        *(short8*)(Kf + base) = ko;
    }

    __syncthreads();

    const int fd = tid >> 6;             // 0..3
    const int lkq = (tid & 63) >> 1, lhi = tid & 1;
#pragma unroll
    for (int hh = 0; hh < 8; hh++) {
        int h = hg * 8 + hh;
        short8 o;
#pragma unroll
        for (int e = 0; e < 8; e++)
            o[e] = (short)Vlds[(hh * 32 + (fd & 1) * 16 + lhi * 8 + e) * 80 + (fd >> 1) * 32 + lkq];
        *(short8*)(Vf + (((size_t)(h * NT + kt) * 4 + fd) << 9) + lkq * 16 + lhi * 8) = o;
    }
}

// ---------------- attention tile: static-max softmax (exp2 domain) + in-reg P + PV ----------------
__device__ __forceinline__ void attn_tile(
    f32x16& st, float& lr, f32x16& o0, f32x16& o1, const short8* vv)
{
    float sum = 0.f;
    float p[16];
#pragma unroll
    for (int r = 0; r < 16; r++) { p[r] = __builtin_amdgcn_exp2f(st[r]); sum += p[r]; }
    lr += sum + __shfl_xor(sum, 32);

    unsigned a0 = cvtpk_bf16(p[0], p[1]),   a1 = cvtpk_bf16(p[2], p[3]);
    unsigned a2 = cvtpk_bf16(p[4], p[5]),   a3 = cvtpk_bf16(p[6], p[7]);
    unsigned a4 = cvtpk_bf16(p[8], p[9]),   a5 = cvtpk_bf16(p[10], p[11]);
    unsigned a6 = cvtpk_bf16(p[12], p[13]), a7 = cvtpk_bf16(p[14], p[15]);
    asm("v_permlane32_swap_b32 %0, %1" : "+v"(a0), "+v"(a2));
    asm("v_permlane32_swap_b32 %0, %1" : "+v"(a1), "+v"(a3));
    asm("v_permlane32_swap_b32 %0, %1" : "+v"(a4), "+v"(a6));
    asm("v_permlane32_swap_b32 %0, %1" : "+v"(a5), "+v"(a7));
    uint4v u0 = {a0, a1, a2, a3}, u1 = {a4, a5, a6, a7};
    short8 pa0, pa1;
    __builtin_memcpy(&pa0, &u0, 16);
    __builtin_memcpy(&pa1, &u1, 16);

    __builtin_amdgcn_s_setprio(1);
    o0 = __builtin_amdgcn_mfma_f32_32x32x16_bf16(pa0, vv[0], o0, 0, 0, 0);
    o0 = __builtin_amdgcn_mfma_f32_32x32x16_bf16(pa1, vv[1], o0, 0, 0, 0);
    o1 = __builtin_amdgcn_mfma_f32_32x32x16_bf16(pa0, vv[2], o1, 0, 0, 0);
    o1 = __builtin_amdgcn_mfma_f32_32x32x16_bf16(pa1, vv[3], o1, 0, 0, 0);
    __builtin_amdgcn_s_setprio(0);
}

// ---------------- flash attention, KV-split, 4 independent waves/block ----------------
__global__ __launch_bounds__(256, 4) void attn_kernel(
    const u16* __restrict__ Qf, const u16* __restrict__ Kf,
    const u16* __restrict__ Vf, u16* __restrict__ part, float* __restrict__ ml)
{
    const int nwg = NSPLIT * NHEAD * QG;             // 1008, %8 == 0
    const int bid = blockIdx.x;
    const int wgid = (bid & 7) * (nwg >> 3) + (bid >> 3);
    const int s   = wgid / (NHEAD * QG);
    const int rem = wgid % (NHEAD * QG);
    const int h   = rem / QG;
    const int qg  = rem % QG;
    const int wid = threadIdx.x >> 6;
    const int qt  = qg * 4 + wid;           // 0..83 (83 = all-pad tile, stores guarded)
    const int lane = threadIdx.x & 63;
    const int kq = lane & 31;
    const int hi = lane >> 5;
    const int q0 = qt * 32;
    const int lxy = kq * 16 + hi * 8;       // chunk offset within fragment plane
    const u16* Kh = Kf + ((size_t)h * NT * 4 << 9);
    const u16* Vh = Vf + ((size_t)h * NT * 4 << 9);

    short8 qf[4];
#pragma unroll
    for (int d = 0; d < 4; d++)
        qf[d] = *(const short8*)(Qf + (((size_t)(h * NT + qt) * 4 + d) << 9) + lxy);

    f32x16 o0 = ZERO16, o1 = ZERO16;
    float lr = 0.f;

    const int ts0 = s * TILES_PER_SPLIT;
    short8 kf[4];
#pragma unroll
    for (int d = 0; d < 4; d++)
        kf[d] = *(const short8*)(Kh + (((size_t)ts0 * 4 + d) << 9) + lxy);

    for (int i = 0; i < TILES_PER_SPLIT; i++) {
        const int tile = ts0 + i;
        const int k0 = tile * 32;
        short8 vv[4];
#pragma unroll
        for (int fd = 0; fd < 4; fd++)
            vv[fd] = *(const short8*)(Vh + (((size_t)tile * 4 + fd) << 9) + lxy);

        f32x16 st = ZERO16;
        __builtin_amdgcn_s_setprio(1);
#pragma unroll
        for (int d = 0; d < 4; d++)
            st = __builtin_amdgcn_mfma_f32_32x32x16_bf16(kf[d], qf[d], st, 0, 0, 0);
        __builtin_amdgcn_s_setprio(0);

        if (i < TILES_PER_SPLIT - 1) {   // prefetch next K tile
#pragma unroll
            for (int d = 0; d < 4; d++)
                kf[d] = *(const short8*)(Kh + (((size_t)(tile + 1) * 4 + d) << 9) + lxy);
        }

        if (k0 + 32 > M_VALID) {         // mask pad keys: exp2(-3e38) == 0
#pragma unroll
            for (int r = 0; r < 16; r++) {
                int key = k0 + (r & 3) + 8 * (r >> 2) + 4 * hi;
                if (key >= M_VALID) st[r] = -3.0e38f;
            }
        }
        attn_tile(st, lr, o0, o1, vv);
    }

    // write bf16 partials (unnormalized), fp32 l
#pragma unroll
    for (int r = 0; r < 16; r++) {
        int rl = (r & 3) + 8 * (r >> 2) + 4 * hi;
        int qrow = q0 + rl;
        if (qrow < M_VALID) {
            u16* pp = part + ((size_t)s * M_PAD + qrow) * DH + h * 64;
            pp[kq] = f2b(o0[r]);
            pp[kq + 32] = f2b(o1[r]);
        }
    }
    if (hi == 0 && q0 + kq < M_VALID)
        ml[((size_t)s * NHEAD + h) * M_PAD + q0 + kq] = lr;
}

// ---------------- merge KV-split partials -> bf16 obf (permuted rows) ----------------
__global__ __launch_bounds__(256) void attn_merge_kernel(
    const u16* __restrict__ part, const float* __restrict__ ml, u16* __restrict__ obf)
{
    const int q = blockIdx.x;           // 0..M_VALID-1
    const int t = threadIdx.x;
    const int h = t >> 4, i = t & 15;   // head, 4-dim group
    float L = 0.f;
#pragma unroll
    for (int s = 0; s < NSPLIT; s++)
        L += ml[((size_t)s * NHEAD + h) * M_PAD + q];
    float inv = 1.0f / L;
    float4 acc = {0.f, 0.f, 0.f, 0.f};
#pragma unroll
    for (int s = 0; s < NSPLIT; s++) {
        short4v v = *(const short4v*)(part + ((size_t)s * M_PAD + q) * DH + h * 64 + i * 4);
        acc.x += b2f((u16)v[0]); acc.y += b2f((u16)v[1]);
        acc.z += b2f((u16)v[2]); acc.w += b2f((u16)v[3]);
    }
    int mrow = (q % 3) * 880 + q / 3;   // (S,T) -> (T,S) permute
    short4v w;
    w[0] = (short)f2b(acc.x * inv); w[1] = (short)f2b(acc.y * inv);
    w[2] = (short)f2b(acc.z * inv); w[3] = (short)f2b(acc.w * inv);
    *(short4v*)(obf + (size_t)mrow * DH + h * 64 + i * 4) = w;
}

// ---------------- launch ----------------
extern "C" void kernel_launch(void* const* d_in, const int* in_sizes, int n_in,
                              void* d_out, int out_size, void* d_ws, size_t ws_size,
                              hipStream_t stream)
{
    const float* x      = (const float*)d_in[0];
    const float* cond   = (const float*)d_in[1];
    const float* w1     = (const float*)d_in[2];
    const float* b1     = (const float*)d_in[3];
    const float* w2     = (const float*)d_in[4];
    const float* b2     = (const float*)d_in[5];
    const float* ln_g   = (const float*)d_in[6];
    const float* ln_b   = (const float*)d_in[7];
    const float* wqkv   = (const float*)d_in[8];
    const float* bqkv   = (const float*)d_in[9];
    const float* qn_w   = (const float*)d_in[10];
    const float* kn_w   = (const float*)d_in[11];
    const float* wproj  = (const float*)d_in[12];
    const float* bproj  = (const float*)d_in[13];
    float* out = (float*)d_out;

    char* ws = (char*)d_ws;
    size_t off = 0;
    auto alloc = [&](size_t bytes) { size_t o = off; off += (bytes + 255) & ~(size_t)255; return o; };

    size_t off_ml     = alloc((size_t)NSPLIT * NHEAD * M_PAD * 4);
    size_t off_w1t    = alloc((size_t)DH * 3072 * 2);
    size_t off_w2t    = alloc((size_t)DH * DH * 2);
    size_t off_wqkvt  = alloc((size_t)3072 * DH * 2);
    size_t off_wprojt = alloc((size_t)CIMG * DH * 2);
    size_t off_h1     = alloc((size_t)M_PAD * DH * 2);   // ┐ attn bf16 partials reuse
    size_t off_h2     = alloc((size_t)M_PAD * DH * 2);   // │ h1..h2ln (3*M_PAD*DH*2 B)
    size_t off_h2ln   = alloc((size_t)M_PAD * DH * 2);   // ┘
    size_t off_qkv    = alloc((size_t)M_PAD * 3072 * 2);
    size_t off_qf     = alloc((size_t)NHEAD * NT * 4 * 512 * 2);
    size_t off_kf     = alloc((size_t)NHEAD * NT * 4 * 512 * 2);
    size_t off_vf     = alloc((size_t)NHEAD * NT * 4 * 512 * 2);
    size_t off_obf    = alloc((size_t)M_PAD * DH * 2);
    size_t off_b1t    = alloc((size_t)3 * DH * 4);
    (void)ws_size;

    u16* w1t    = (u16*)(ws + off_w1t);
    u16* w2t    = (u16*)(ws + off_w2t);
    u16* wqkvt  = (u16*)(ws + off_wqkvt);
    u16* wprojt = (u16*)(ws + off_wprojt);
    u16* h1     = (u16*)(ws + off_h1);
    u16* h2     = (u16*)(ws + off_h2);
    u16* h2ln   = (u16*)(ws + off_h2ln);
    u16* qkvb   = (u16*)(ws + off_qkv);
    u16* Qf     = (u16*)(ws + off_qf);
    u16* Kf     = (u16*)(ws + off_kf);
    u16* Vf     = (u16*)(ws + off_vf);
    u16* obf    = (u16*)(ws + off_obf);
    float* b1t  = (float*)(ws + off_b1t);
    u16* apart  = (u16*)(ws + off_h1);       // attn bf16 partials over dead h1..h2ln
    float* mlbf = (float*)(ws + off_ml);

    bias1t_kernel<<<dim3(3, 4), 256, 0, stream>>>(w1, b1, cond, b1t);
    transpose_all_kernel<<<10240, 256, 0, stream>>>(w1, w2, wqkv, wproj, w1t, w2t, wqkvt, wprojt);

    // gemm1: A = fp32 x converted in-register during staging (build_fused eliminated)
    gemm_kernel<0, 64, 64, true><<<dim3((DH / 64) * (M_PAD / 64)), 256, 0, stream>>>(
        x, w1t, b1t, nullptr, h1, nullptr, DH, 3072, 3072, 3072, M_PAD);
    gemm_kernel<1, 64, 64, false><<<dim3((DH / 64) * (M_PAD / 64)), 256, 0, stream>>>(
        h1, w2t, b2, nullptr, h2, nullptr, DH, DH, DH, DH, M_PAD);
    ln_kernel<<<M_PAD, 256, 0, stream>>>(h2, ln_g, ln_b, h2ln);
    gemm_kernel<1, 128, 128, false><<<dim3((3072 / 128) * (M_PAD / 128)), 256, 0, stream>>>(
        h2ln, wqkvt, bqkv, nullptr, qkvb, nullptr, 3072, DH, DH, DH, M_PAD);
    fragmentize_kernel<<<dim3(NT, 2), 256, 0, stream>>>(qkvb, qn_w, kn_w, Qf, Kf, Vf);
    attn_kernel<<<dim3(NSPLIT * NHEAD * QG), 256, 0, stream>>>(Qf, Kf, Vf, apart, mlbf);
    attn_merge_kernel<<<M_VALID, 256, 0, stream>>>(apart, mlbf, obf);
    gemm_kernel<2, 128, 128, false><<<dim3((CIMG / 128) * (M_PAD / 128)), 256, 0, stream>>>(
        obf, wprojt, bproj, x, nullptr, out, CIMG, DH, DH, DH, M_VALID);
}

// Round 20
// 188.258 us; speedup vs baseline: 1.1115x; 1.1115x over previous
//
#include <hip/hip_runtime.h>
#include <hip/hip_bf16.h>

typedef __attribute__((ext_vector_type(8))) short short8;
typedef __attribute__((ext_vector_type(4))) short short4v;
typedef __attribute__((ext_vector_type(4))) unsigned uint4v;
typedef __attribute__((ext_vector_type(4))) float f32x4;
typedef __attribute__((ext_vector_type(16))) float f32x16;
typedef unsigned short u16;

#define ZERO16 (f32x16){0,0,0,0,0,0,0,0,0,0,0,0,0,0,0,0}

__device__ __forceinline__ float b2f(u16 h) {
    unsigned u = ((unsigned)h) << 16;
    float f; __builtin_memcpy(&f, &u, 4); return f;
}
__device__ __forceinline__ u16 f2b(float f) {   // RTNE via HIP intrinsic
    __hip_bfloat16 h = __float2bfloat16(f);
    u16 r; __builtin_memcpy(&r, &h, 2); return r;
}
__device__ __forceinline__ void gload16(const void* g, void* l) {
    __builtin_amdgcn_global_load_lds(
        (const __attribute__((address_space(1))) unsigned*)g,
        (__attribute__((address_space(3))) unsigned*)l, 16, 0, 0);
}
__device__ __forceinline__ unsigned cvtpk_bf16(float lo, float hi) {
    unsigned d;
    asm("v_cvt_pk_bf16_f32 %0, %1, %2" : "=v"(d) : "v"(lo), "v"(hi));
    return d;
}

// ---------------- problem constants ----------------
#define M_VALID 2640          // B*S*T tokens
#define M_PAD   2688          // 21 * 128
#define K1P     3072          // gemm1 K (mouse cols folded into per-frame bias)
#define DH      1024
#define CIMG    3072
#define NHEAD   16
#define NT      84            // 32-token tiles (2688 tokens)
#define QG      21            // q-tile groups of 4 (4 waves/block)
#define NSPLIT  3
#define TILES_PER_SPLIT 28    // 3*28 = 84 tiles
#define LOG2E   1.4426950408889634f

// ---------------- build fused input (bf16, 3072 cols only) ----------------
__global__ __launch_bounds__(256) void build_fused_kernel(
    const float* __restrict__ x, u16* __restrict__ fused)
{
    int n = blockIdx.x;
    int tid = threadIdx.x;
    const float* xr = x + (size_t)n * CIMG;
    u16* fr = fused + (size_t)n * K1P;
    for (int c = tid * 4; c < CIMG; c += 1024) {
        float4 v = *(const float4*)(xr + c);
        short4v w;
        w[0] = (short)f2b(v.x); w[1] = (short)f2b(v.y);
        w[2] = (short)f2b(v.z); w[3] = (short)f2b(v.w);
        *(short4v*)(fr + c) = w;
    }
}

// ---------------- per-frame bias for gemm1: bias1t[t] = b1 + mouse[t] @ W1[3072:] ----------------
__global__ __launch_bounds__(256) void bias1t_kernel(
    const float* __restrict__ w1, const float* __restrict__ b1,
    const float* __restrict__ cond, float* __restrict__ bias1t)
{
    int t = blockIdx.x;                       // 0..2
    int col = blockIdx.y * 256 + threadIdx.x;
    float v = b1[col];
#pragma unroll
    for (int j = 0; j < 24; j++) {
        int f = t * 4 + (j >> 1);             // row in mouse_padded (first 8 zero)
        if (f >= 8) v += cond[(f - 8) * 2 + (j & 1)] * w1[(size_t)(3072 + j) * DH + col];
    }
    bias1t[t * DH + col] = v;
}

// ---------------- all 4 weight transposes, one dispatch ----------------
__global__ __launch_bounds__(256) void transpose_all_kernel(
    const float* __restrict__ w1, const float* __restrict__ w2,
    const float* __restrict__ wqkv, const float* __restrict__ wproj,
    u16* __restrict__ w1t, u16* __restrict__ w2t,
    u16* __restrict__ wqkvt, u16* __restrict__ wprojt)
{
    int b = blockIdx.x;
    const float* W; u16* Wt; int K, N, ldt, nx;
    if (b < 3072)      {            W = w1;    Wt = w1t;    K = 3072; N = DH;   ldt = 3072; nx = 32; }
    else if (b < 4096) { b -= 3072; W = w2;    Wt = w2t;    K = DH;   N = DH;   ldt = DH;   nx = 32; }
    else if (b < 7168) { b -= 4096; W = wqkv;  Wt = wqkvt;  K = DH;   N = 3072; ldt = DH;   nx = 96; }
    else               { b -= 7168; W = wproj; Wt = wprojt; K = DH;   N = CIMG; ldt = DH;   nx = 96; }
    __shared__ float t[32][33];
    int n0 = (b % nx) * 32, k0 = (b / nx) * 32;
    int x = threadIdx.x & 31, y0 = threadIdx.x >> 5;   // 32x8
    for (int yy = y0; yy < 32; yy += 8) {
        int k = k0 + yy, n = n0 + x;
        t[yy][x] = (k < K && n < N) ? W[(size_t)k * N + n] : 0.f;
    }
    __syncthreads();
    for (int yy = y0; yy < 32; yy += 8) {
        int n = n0 + yy, k = k0 + x;
        if (n < N && k < ldt) Wt[(size_t)n * ldt + k] = f2b(t[x][yy]);
    }
}

// ---------------- GEMM: C[M][N] = A[M][K] @ Bt[N][K]^T  (bf16 in, f32 acc) ----------------
// 2-phase pipeline, BK=64 dbuf LDS, XOR-16B swizzle (pre-swizzled source),
// XCD-chunked block swizzle, LDS-bounce coalesced epilogue.
// EPI 0: per-(row%3) bias + GELU -> bf16. EPI 1: bias -> bf16. EPI 2: bias+resid -> f32.
template<int EPI, int BM, int BN>
__global__ __launch_bounds__(256) void gemm_kernel(
    const u16* __restrict__ A, const u16* __restrict__ Bt,
    const float* __restrict__ bias, const float* __restrict__ resid,
    u16* __restrict__ Cb, float* __restrict__ Cf,
    int N, int K, int Mvalid)
{
    constexpr int MI  = BM / 32;
    constexpr int NJ  = BN / 32;
    constexpr int CA  = BM / 32;
    constexpr int CB  = BN / 32;
    constexpr unsigned ABYTES = BM * 128;
    constexpr unsigned BBYTES = BN * 128;
    constexpr unsigned STG = 2 * (ABYTES + BBYTES);
    constexpr unsigned CTW = BN + 4;
    constexpr unsigned CTB = BM * CTW * 4;
    constexpr int TPR = 256 / BM;
    __shared__ __align__(16) char smem[STG > CTB ? STG : CTB];

    const int tid = threadIdx.x;
    const int lane = tid & 63, wid = tid >> 6;
    const int l15 = lane & 15, l4 = lane >> 4;

    const int nx = N / BN;
    const int nwg = nx * (M_PAD / BM);
    const int bid = blockIdx.x;
    const int wgid = (bid & 7) * (nwg >> 3) + (bid >> 3);
    const int m0 = (wgid / nx) * BM, n0 = (wgid % nx) * BN;

    const int wr = (wid >> 1) * (BM / 2), wc = (wid & 1) * (BN / 2);

    const int srow = lane >> 3;
    const int scol = ((lane & 7) ^ (lane >> 3)) << 3;

    f32x4 acc[MI][NJ];
#pragma unroll
    for (int i = 0; i < MI; i++)
#pragma unroll
        for (int j = 0; j < NJ; j++) acc[i][j] = (f32x4){0.f, 0.f, 0.f, 0.f};

    const int nt = K >> 6;

    auto stage = [&](int buf, int k0) {
        char* Ab = smem + buf * ABYTES;
        char* Bb = smem + 2 * ABYTES + buf * BBYTES;
#pragma unroll
        for (int i = 0; i < CA; i++) {
            int c = wid * CA + i;
            gload16(A + (size_t)(m0 + c * 8 + srow) * K + k0 + scol,
                    Ab + c * 1024 + lane * 16);
        }
#pragma unroll
        for (int i = 0; i < CB; i++) {
            int c = wid * CB + i;
            gload16(Bt + (size_t)(n0 + c * 8 + srow) * K + k0 + scol,
                    Bb + c * 1024 + lane * 16);
        }
    };

    stage(0, 0);
    __syncthreads();
    int cur = 0;
    for (int t = 0; t < nt; t++) {
        if (t + 1 < nt) stage(cur ^ 1, (t + 1) * 64);
        const char* Ab = smem + cur * ABYTES;
        const char* Bb = smem + 2 * ABYTES + cur * BBYTES;
#pragma unroll
        for (int ki = 0; ki < 2; ki++) {
            short8 af[MI], bfr[NJ];
#pragma unroll
            for (int i = 0; i < MI; i++) {
                int row = wr + i * 16 + l15;
                af[i] = *(const short8*)(Ab + row * 128 + (((ki * 4 + l4) ^ (l15 & 7)) << 4));
            }
#pragma unroll
            for (int j = 0; j < NJ; j++) {
                int row = wc + j * 16 + l15;
                bfr[j] = *(const short8*)(Bb + row * 128 + (((ki * 4 + l4) ^ (l15 & 7)) << 4));
            }
            __builtin_amdgcn_s_setprio(1);
#pragma unroll
            for (int i = 0; i < MI; i++)
#pragma unroll
                for (int j = 0; j < NJ; j++)
                    acc[i][j] = __builtin_amdgcn_mfma_f32_16x16x32_bf16(af[i], bfr[j], acc[i][j], 0, 0, 0);
            __builtin_amdgcn_s_setprio(0);
        }
        __syncthreads();
        cur ^= 1;
    }

    // ---- LDS-bounce epilogue ----
    float* Ct = (float*)smem;
#pragma unroll
    for (int i = 0; i < MI; i++)
#pragma unroll
        for (int j = 0; j < NJ; j++)
#pragma unroll
            for (int r = 0; r < 4; r++)
                Ct[(wr + i * 16 + l4 * 4 + r) * CTW + wc + j * 16 + l15] = acc[i][j][r];
    __syncthreads();

    const int row = tid / TPR;
    const int cb  = (tid % TPR) * (BN / TPR);
    const int grow = m0 + row;
    const int gcol = n0 + cb;
    if (EPI == 2) {
        if (grow < Mvalid) {
#pragma unroll
            for (int u = 0; u < BN / (4 * TPR); u++) {
                f32x4 v = *(const f32x4*)&Ct[row * CTW + cb + u * 4];
                float4 bv = *(const float4*)&bias[gcol + u * 4];
                float4 rv = *(const float4*)&resid[(size_t)grow * N + gcol + u * 4];
                float4 o;
                o.x = v[0] + bv.x + rv.x; o.y = v[1] + bv.y + rv.y;
                o.z = v[2] + bv.z + rv.z; o.w = v[3] + bv.w + rv.w;
                *(float4*)&Cf[(size_t)grow * N + gcol + u * 4] = o;
            }
        }
    } else {
        const float* bb = bias + (EPI == 0 ? (size_t)(grow % 3) * N : 0);
        u16 tmp[BN / TPR];
#pragma unroll
        for (int u = 0; u < BN / (4 * TPR); u++) {
            f32x4 v = *(const f32x4*)&Ct[row * CTW + cb + u * 4];
            float4 bv = *(const float4*)&bb[gcol + u * 4];
#pragma unroll
            for (int e = 0; e < 4; e++) {
                float val = v[e] + ((const float*)&bv)[e];
                if (EPI == 0) {
                    float tt = val + 0.044715f * val * val * val;
                    val = 0.5f * val * (1.0f + tanhf(0.7978845608028654f * tt));
                }
                tmp[u * 4 + e] = f2b(val);
            }
        }
#pragma unroll
        for (int u = 0; u < BN / (8 * TPR); u++)
            *(short8*)(Cb + (size_t)grow * N + gcol + u * 8) = *(const short8*)&tmp[u * 8];
    }
}

// ---------------- LayerNorm over 1024 (bf16 -> bf16) ----------------
__global__ __launch_bounds__(256) void ln_kernel(
    const u16* __restrict__ h2, const float* __restrict__ g,
    const float* __restrict__ b, u16* __restrict__ out)
{
    int row = blockIdx.x;
    int tid = threadIdx.x;
    const u16* p = h2 + (size_t)row * DH;
    float v[4];
#pragma unroll
    for (int i = 0; i < 4; i++) v[i] = b2f(p[tid * 4 + i]);
    float s1 = v[0] + v[1] + v[2] + v[3];
    float s2 = v[0]*v[0] + v[1]*v[1] + v[2]*v[2] + v[3]*v[3];
    for (int m = 1; m < 64; m <<= 1) { s1 += __shfl_xor(s1, m); s2 += __shfl_xor(s2, m); }
    __shared__ float a1[4], a2[4];
    int w = tid >> 6;
    if ((tid & 63) == 0) { a1[w] = s1; a2[w] = s2; }
    __syncthreads();
    s1 = a1[0] + a1[1] + a1[2] + a1[3];
    s2 = a2[0] + a2[1] + a2[2] + a2[3];
    float mean = s1 * (1.0f / 1024.0f);
    float var = s2 * (1.0f / 1024.0f) - mean * mean;
    float rs = rsqrtf(var + 1e-5f);
    u16* q = out + (size_t)row * DH;
#pragma unroll
    for (int i = 0; i < 4; i++) {
        int c = tid * 4 + i;
        q[c] = f2b((v[i] - mean) * rs * g[c] + b[c]);
    }
}

// ---------------- fragmentize: RMSNorm(q,k) + MFMA-fragment layout for Q,K,V ----------------
__global__ __launch_bounds__(256) void fragmentize_kernel(
    const u16* __restrict__ qkv, const float* __restrict__ qw, const float* __restrict__ kw,
    u16* __restrict__ Qf, u16* __restrict__ Kf, u16* __restrict__ Vf)
{
    __shared__ u16 Vlds[8 * 32 * 80];    // [hh][token][dim], row stride 80
    const int kt = blockIdx.x;           // 0..NT-1
    const int hg = blockIdx.y;           // 0..1 (8 heads each)
    const int tid = threadIdx.x;
    const int t32 = tid >> 3, c8 = tid & 7;
    const int n = kt * 32 + t32;
    const u16* row = qkv + (size_t)n * 3072;

#pragma unroll
    for (int hh = 0; hh < 8; hh++) {
        short8 v = *(const short8*)(row + 2048 + (hg * 8 + hh) * 64 + c8 * 8);
        *(short8*)(&Vlds[(hh * 32 + t32) * 80 + c8 * 8]) = v;
    }

    float sq[8], sk[8];
#pragma unroll
    for (int hh = 0; hh < 8; hh++) {
        int h = hg * 8 + hh;
        short8 qv = *(const short8*)(row + h * 64 + c8 * 8);
        short8 kv = *(const short8*)(row + 1024 + h * 64 + c8 * 8);
        float aq = 0.f, ak = 0.f;
#pragma unroll
        for (int e = 0; e < 8; e++) {
            float fq = b2f((u16)qv[e]); aq += fq * fq;
            float fk = b2f((u16)kv[e]); ak += fk * fk;
        }
        sq[hh] = aq; sk[hh] = ak;
    }
#pragma unroll
    for (int m = 1; m < 8; m <<= 1) {
#pragma unroll
        for (int hh = 0; hh < 8; hh++) {
            sq[hh] += __shfl_xor(sq[hh], m);
            sk[hh] += __shfl_xor(sk[hh], m);
        }
    }

    float qwv[8], kwv[8];
#pragma unroll
    for (int e = 0; e < 8; e++) { qwv[e] = qw[c8 * 8 + e]; kwv[e] = kw[c8 * 8 + e]; }

#pragma unroll
    for (int hh = 0; hh < 8; hh++) {
        int h = hg * 8 + hh;
        float rq = rsqrtf(sq[hh] * (1.0f / 64.0f) + 1e-6f) * (0.125f * LOG2E);
        float rk = rsqrtf(sk[hh] * (1.0f / 64.0f) + 1e-6f);
        short8 qv = *(const short8*)(row + h * 64 + c8 * 8);
        short8 kv = *(const short8*)(row + 1024 + h * 64 + c8 * 8);
        short8 qo, ko;
#pragma unroll
        for (int e = 0; e < 8; e++) {
            qo[e] = (short)f2b(b2f((u16)qv[e]) * rq * qwv[e]);
            ko[e] = (short)f2b(b2f((u16)kv[e]) * rk * kwv[e]);
        }
        size_t base = (((size_t)(h * NT + kt) * 4 + (c8 >> 1)) << 9) + t32 * 16 + (c8 & 1) * 8;
        *(short8*)(Qf + base) = qo;
        *(short8*)(Kf + base) = ko;
    }

    __syncthreads();

    const int fd = tid >> 6;             // 0..3
    const int lkq = (tid & 63) >> 1, lhi = tid & 1;
#pragma unroll
    for (int hh = 0; hh < 8; hh++) {
        int h = hg * 8 + hh;
        short8 o;
#pragma unroll
        for (int e = 0; e < 8; e++)
            o[e] = (short)Vlds[(hh * 32 + (fd & 1) * 16 + lhi * 8 + e) * 80 + (fd >> 1) * 32 + lkq];
        *(short8*)(Vf + (((size_t)(h * NT + kt) * 4 + fd) << 9) + lkq * 16 + lhi * 8) = o;
    }
}

// ---------------- attention tile: static-max softmax (exp2 domain) + in-reg P + PV ----------------
__device__ __forceinline__ void attn_tile(
    f32x16& st, float& lr, f32x16& o0, f32x16& o1, const short8* vv)
{
    float sum = 0.f;
    float p[16];
#pragma unroll
    for (int r = 0; r < 16; r++) { p[r] = __builtin_amdgcn_exp2f(st[r]); sum += p[r]; }
    lr += sum + __shfl_xor(sum, 32);

    unsigned a0 = cvtpk_bf16(p[0], p[1]),   a1 = cvtpk_bf16(p[2], p[3]);
    unsigned a2 = cvtpk_bf16(p[4], p[5]),   a3 = cvtpk_bf16(p[6], p[7]);
    unsigned a4 = cvtpk_bf16(p[8], p[9]),   a5 = cvtpk_bf16(p[10], p[11]);
    unsigned a6 = cvtpk_bf16(p[12], p[13]), a7 = cvtpk_bf16(p[14], p[15]);
    asm("v_permlane32_swap_b32 %0, %1" : "+v"(a0), "+v"(a2));
    asm("v_permlane32_swap_b32 %0, %1" : "+v"(a1), "+v"(a3));
    asm("v_permlane32_swap_b32 %0, %1" : "+v"(a4), "+v"(a6));
    asm("v_permlane32_swap_b32 %0, %1" : "+v"(a5), "+v"(a7));
    uint4v u0 = {a0, a1, a2, a3}, u1 = {a4, a5, a6, a7};
    short8 pa0, pa1;
    __builtin_memcpy(&pa0, &u0, 16);
    __builtin_memcpy(&pa1, &u1, 16);

    __builtin_amdgcn_s_setprio(1);
    o0 = __builtin_amdgcn_mfma_f32_32x32x16_bf16(pa0, vv[0], o0, 0, 0, 0);
    o0 = __builtin_amdgcn_mfma_f32_32x32x16_bf16(pa1, vv[1], o0, 0, 0, 0);
    o1 = __builtin_amdgcn_mfma_f32_32x32x16_bf16(pa0, vv[2], o1, 0, 0, 0);
    o1 = __builtin_amdgcn_mfma_f32_32x32x16_bf16(pa1, vv[3], o1, 0, 0, 0);
    __builtin_amdgcn_s_setprio(0);
}

// ---------------- flash attention, KV-split, 4 independent waves/block ----------------
__global__ __launch_bounds__(256, 4) void attn_kernel(
    const u16* __restrict__ Qf, const u16* __restrict__ Kf,
    const u16* __restrict__ Vf, u16* __restrict__ part, float* __restrict__ ml)
{
    const int nwg = NSPLIT * NHEAD * QG;             // 1008, %8 == 0
    const int bid = blockIdx.x;
    const int wgid = (bid & 7) * (nwg >> 3) + (bid >> 3);
    const int s   = wgid / (NHEAD * QG);
    const int rem = wgid % (NHEAD * QG);
    const int h   = rem / QG;
    const int qg  = rem % QG;
    const int wid = threadIdx.x >> 6;
    const int qt  = qg * 4 + wid;           // 0..83 (83 = all-pad tile, stores guarded)
    const int lane = threadIdx.x & 63;
    const int kq = lane & 31;
    const int hi = lane >> 5;
    const int q0 = qt * 32;
    const int lxy = kq * 16 + hi * 8;       // chunk offset within fragment plane
    const u16* Kh = Kf + ((size_t)h * NT * 4 << 9);
    const u16* Vh = Vf + ((size_t)h * NT * 4 << 9);

    short8 qf[4];
#pragma unroll
    for (int d = 0; d < 4; d++)
        qf[d] = *(const short8*)(Qf + (((size_t)(h * NT + qt) * 4 + d) << 9) + lxy);

    f32x16 o0 = ZERO16, o1 = ZERO16;
    float lr = 0.f;

    const int ts0 = s * TILES_PER_SPLIT;
    short8 kf[4];
#pragma unroll
    for (int d = 0; d < 4; d++)
        kf[d] = *(const short8*)(Kh + (((size_t)ts0 * 4 + d) << 9) + lxy);

    for (int i = 0; i < TILES_PER_SPLIT; i++) {
        const int tile = ts0 + i;
        const int k0 = tile * 32;
        short8 vv[4];
#pragma unroll
        for (int fd = 0; fd < 4; fd++)
            vv[fd] = *(const short8*)(Vh + (((size_t)tile * 4 + fd) << 9) + lxy);

        f32x16 st = ZERO16;
        __builtin_amdgcn_s_setprio(1);
#pragma unroll
        for (int d = 0; d < 4; d++)
            st = __builtin_amdgcn_mfma_f32_32x32x16_bf16(kf[d], qf[d], st, 0, 0, 0);
        __builtin_amdgcn_s_setprio(0);

        if (i < TILES_PER_SPLIT - 1) {   // prefetch next K tile
#pragma unroll
            for (int d = 0; d < 4; d++)
                kf[d] = *(const short8*)(Kh + (((size_t)(tile + 1) * 4 + d) << 9) + lxy);
        }

        if (k0 + 32 > M_VALID) {         // mask pad keys: exp2(-3e38) == 0
#pragma unroll
            for (int r = 0; r < 16; r++) {
                int key = k0 + (r & 3) + 8 * (r >> 2) + 4 * hi;
                if (key >= M_VALID) st[r] = -3.0e38f;
            }
        }
        attn_tile(st, lr, o0, o1, vv);
    }

    // write bf16 partials (unnormalized), fp32 l
#pragma unroll
    for (int r = 0; r < 16; r++) {
        int rl = (r & 3) + 8 * (r >> 2) + 4 * hi;
        int qrow = q0 + rl;
        if (qrow < M_VALID) {
            u16* pp = part + ((size_t)s * M_PAD + qrow) * DH + h * 64;
            pp[kq] = f2b(o0[r]);
            pp[kq + 32] = f2b(o1[r]);
        }
    }
    if (hi == 0 && q0 + kq < M_VALID)
        ml[((size_t)s * NHEAD + h) * M_PAD + q0 + kq] = lr;
}

// ---------------- merge KV-split partials -> bf16 obf (permuted rows) ----------------
__global__ __launch_bounds__(256) void attn_merge_kernel(
    const u16* __restrict__ part, const float* __restrict__ ml, u16* __restrict__ obf)
{
    const int q = blockIdx.x;           // 0..M_VALID-1
    const int t = threadIdx.x;
    const int h = t >> 4, i = t & 15;   // head, 4-dim group
    float L = 0.f;
#pragma unroll
    for (int s = 0; s < NSPLIT; s++)
        L += ml[((size_t)s * NHEAD + h) * M_PAD + q];
    float inv = 1.0f / L;
    float4 acc = {0.f, 0.f, 0.f, 0.f};
#pragma unroll
    for (int s = 0; s < NSPLIT; s++) {
        short4v v = *(const short4v*)(part + ((size_t)s * M_PAD + q) * DH + h * 64 + i * 4);
        acc.x += b2f((u16)v[0]); acc.y += b2f((u16)v[1]);
        acc.z += b2f((u16)v[2]); acc.w += b2f((u16)v[3]);
    }
    int mrow = (q % 3) * 880 + q / 3;   // (S,T) -> (T,S) permute
    short4v w;
    w[0] = (short)f2b(acc.x * inv); w[1] = (short)f2b(acc.y * inv);
    w[2] = (short)f2b(acc.z * inv); w[3] = (short)f2b(acc.w * inv);
    *(short4v*)(obf + (size_t)mrow * DH + h * 64 + i * 4) = w;
}

// ---------------- launch ----------------
extern "C" void kernel_launch(void* const* d_in, const int* in_sizes, int n_in,
                              void* d_out, int out_size, void* d_ws, size_t ws_size,
                              hipStream_t stream)
{
    const float* x      = (const float*)d_in[0];
    const float* cond   = (const float*)d_in[1];
    const float* w1     = (const float*)d_in[2];
    const float* b1     = (const float*)d_in[3];
    const float* w2     = (const float*)d_in[4];
    const float* b2     = (const float*)d_in[5];
    const float* ln_g   = (const float*)d_in[6];
    const float* ln_b   = (const float*)d_in[7];
    const float* wqkv   = (const float*)d_in[8];
    const float* bqkv   = (const float*)d_in[9];
    const float* qn_w   = (const float*)d_in[10];
    const float* kn_w   = (const float*)d_in[11];
    const float* wproj  = (const float*)d_in[12];
    const float* bproj  = (const float*)d_in[13];
    float* out = (float*)d_out;

    char* ws = (char*)d_ws;
    size_t off = 0;
    auto alloc = [&](size_t bytes) { size_t o = off; off += (bytes + 255) & ~(size_t)255; return o; };

    size_t off_fused  = alloc((size_t)M_PAD * K1P * 2);
    size_t off_w1t    = alloc((size_t)DH * K1P * 2);
    size_t off_w2t    = alloc((size_t)DH * DH * 2);
    size_t off_wqkvt  = alloc((size_t)3072 * DH * 2);
    size_t off_wprojt = alloc((size_t)CIMG * DH * 2);
    size_t off_h1     = alloc((size_t)M_PAD * DH * 2);   // ┐ attn bf16 partials reuse
    size_t off_h2     = alloc((size_t)M_PAD * DH * 2);   // │ h1..h2ln (3*M_PAD*DH*2 B)
    size_t off_h2ln   = alloc((size_t)M_PAD * DH * 2);   // ┘
    size_t off_qkv    = alloc((size_t)M_PAD * 3072 * 2);
    size_t off_qf     = alloc((size_t)NHEAD * NT * 4 * 512 * 2);
    size_t off_kf     = alloc((size_t)NHEAD * NT * 4 * 512 * 2);
    size_t off_vf     = alloc((size_t)NHEAD * NT * 4 * 512 * 2);
    size_t off_obf    = alloc((size_t)M_PAD * DH * 2);
    size_t off_b1t    = alloc((size_t)3 * DH * 4);
    (void)ws_size;

    u16* fused  = (u16*)(ws + off_fused);
    u16* w1t    = (u16*)(ws + off_w1t);
    u16* w2t    = (u16*)(ws + off_w2t);
    u16* wqkvt  = (u16*)(ws + off_wqkvt);
    u16* wprojt = (u16*)(ws + off_wprojt);
    u16* h1     = (u16*)(ws + off_h1);
    u16* h2     = (u16*)(ws + off_h2);
    u16* h2ln   = (u16*)(ws + off_h2ln);
    u16* qkvb   = (u16*)(ws + off_qkv);
    u16* Qf     = (u16*)(ws + off_qf);
    u16* Kf     = (u16*)(ws + off_kf);
    u16* Vf     = (u16*)(ws + off_vf);
    u16* obf    = (u16*)(ws + off_obf);
    float* b1t  = (float*)(ws + off_b1t);
    u16* apart  = (u16*)(ws + off_h1);       // attn bf16 partials over dead h1..h2ln
    float* mlbf = (float*)(ws + off_fused);  // over dead fused (rewritten each launch)

    build_fused_kernel<<<M_VALID, 256, 0, stream>>>(x, fused);
    bias1t_kernel<<<dim3(3, 4), 256, 0, stream>>>(w1, b1, cond, b1t);
    transpose_all_kernel<<<10240, 256, 0, stream>>>(w1, w2, wqkv, wproj, w1t, w2t, wqkvt, wprojt);

    gemm_kernel<0, 64, 64><<<dim3((DH / 64) * (M_PAD / 64)), 256, 0, stream>>>(
        fused, w1t, b1t, nullptr, h1, nullptr, DH, K1P, M_PAD);
    gemm_kernel<1, 64, 64><<<dim3((DH / 64) * (M_PAD / 64)), 256, 0, stream>>>(
        h1, w2t, b2, nullptr, h2, nullptr, DH, DH, M_PAD);
    ln_kernel<<<M_PAD, 256, 0, stream>>>(h2, ln_g, ln_b, h2ln);
    gemm_kernel<1, 128, 128><<<dim3((3072 / 128) * (M_PAD / 128)), 256, 0, stream>>>(
        h2ln, wqkvt, bqkv, nullptr, qkvb, nullptr, 3072, DH, M_PAD);
    fragmentize_kernel<<<dim3(NT, 2), 256, 0, stream>>>(qkvb, qn_w, kn_w, Qf, Kf, Vf);
    attn_kernel<<<dim3(NSPLIT * NHEAD * QG), 256, 0, stream>>>(Qf, Kf, Vf, apart, mlbf);
    attn_merge_kernel<<<M_VALID, 256, 0, stream>>>(apart, mlbf, obf);
    gemm_kernel<2, 128, 128><<<dim3((CIMG / 128) * (M_PAD / 128)), 256, 0, stream>>>(
        obf, wprojt, bproj, x, nullptr, out, CIMG, DH, M_VALID);
}